// Round 5
// baseline (177.680 us; speedup 1.0000x reference)
//
#include <hip/hip_runtime.h>

#define NTOT  16384
#define NFEAT 300
#define NHID  512
#define NOUT  256
#define NACT  64
#define NEIGH 2048
#define SSZ   2112   // NACT + NEIGH
#define CSTR  64     // cols row stride
#define GEMMT 528    // 66 x 8 tiles of 32x64
#define K1BLK (SSZ + GEMMT + 8 + 1)   // 2649
#define K2BLK 528    // 4 waves/block, one wave per row

union SM1 {
    struct { int scur[2304]; unsigned long long smask[9][4]; int spre[40]; } scan;
    struct { float As[16][36]; float Bs[16][64]; } gemm;
};

// ===== K1: scan (blocks <SSZ) || gemm || u=W2@iw || nb-out + ticket reset ====
__global__ __launch_bounds__(256) void k_front(
        const float* __restrict__ adj, const int* __restrict__ act,
        const int* __restrict__ nb,  const float* __restrict__ x,
        const float* __restrict__ W1, const float* __restrict__ W2,
        const float* __restrict__ iw,
        int* __restrict__ cnt, unsigned short* __restrict__ cols,
        float* __restrict__ B1, float* __restrict__ u,
        float* __restrict__ out, int* __restrict__ ticket)
{
    __shared__ SM1 sm;
    const int t = threadIdx.x;
    const int w = t >> 6, lane = t & 63;
    const int bid = blockIdx.x;

    if (bid < SSZ) {
        // ---------------- ballot scan, one subgraph row per block ----------
        for (int k = t; k < 2304; k += 256)
            sm.scan.scur[k] = (k < NACT) ? act[k] : (k < SSZ ? nb[k - NACT] : 0);
        __syncthreads();
        const int row = bid;
        const float* arow = adj + (size_t)sm.scan.scur[row] * NTOT;
        float val[9];
#pragma unroll
        for (int k = 0; k < 9; ++k) val[k] = arow[sm.scan.scur[t + (k << 8)]];
        bool hit[9];
#pragma unroll
        for (int k = 0; k < 9; ++k) {
            int j = t + (k << 8);
            hit[k] = (j < SSZ) && (val[k] != 0.0f);
            unsigned long long m = __ballot(hit[k]);
            if (lane == 0) sm.scan.smask[k][w] = m;
        }
        __syncthreads();
        if (t < 64) {                            // prefix over 36 groups
            int c = (t < 36) ? __popcll(sm.scan.smask[t >> 2][t & 3]) : 0;
            int vv = c;
#pragma unroll
            for (int o = 1; o < 64; o <<= 1) {
                int xx = __shfl_up(vv, o, 64);
                if (lane >= o) vv += xx;
            }
            if (t == 0) sm.scan.spre[0] = 0;
            if (t < 36) sm.scan.spre[t + 1] = vv;
        }
        __syncthreads();
        unsigned short* dst = cols + (size_t)row * CSTR;
#pragma unroll
        for (int k = 0; k < 9; ++k) {
            if (hit[k]) {
                unsigned long long below = sm.scan.smask[k][w] & ((1ull << lane) - 1ull);
                dst[sm.scan.spre[k * 4 + w] + __popcll(below)] =
                    (unsigned short)(t + (k << 8));
            }
        }
        if (t == 0) cnt[row] = sm.scan.spre[36];
    } else if (bid < SSZ + GEMMT) {
        // ---------------- GEMM tile 32x64 of X[cur] @ W1 --------------------
        int it = bid - SSZ;
        int bm = (it % 66) * 32, bn = (it / 66) * 64;
        int tx = t & 15, ty = t >> 4;
        float acc[2][4] = {};
        for (int kt = 0; kt < NFEAT; kt += 16) {
#pragma unroll
            for (int l = 0; l < 2; ++l) {
                int idx = t + l * 256;
                int m = idx >> 4, kk = idx & 15;
                int gk = kt + kk, gm = bm + m;
                int ar = (gm < NACT) ? act[gm] : nb[gm - NACT];
                sm.gemm.As[kk][m] = (gk < NFEAT) ? x[(size_t)ar * NFEAT + gk] : 0.0f;
            }
#pragma unroll
            for (int l = 0; l < 4; ++l) {
                int idx = t + l * 256;
                int nn = idx & 63, kk = idx >> 6;
                int gk = kt + kk;
                sm.gemm.Bs[kk][nn] = (gk < NFEAT) ? W1[(size_t)gk * NHID + bn + nn] : 0.0f;
            }
            __syncthreads();
#pragma unroll
            for (int kk = 0; kk < 16; ++kk) {
                float a0 = sm.gemm.As[kk][ty * 2], a1 = sm.gemm.As[kk][ty * 2 + 1];
                float4 bv = *(const float4*)&sm.gemm.Bs[kk][tx * 4];
                acc[0][0] += a0 * bv.x; acc[0][1] += a0 * bv.y;
                acc[0][2] += a0 * bv.z; acc[0][3] += a0 * bv.w;
                acc[1][0] += a1 * bv.x; acc[1][1] += a1 * bv.y;
                acc[1][2] += a1 * bv.z; acc[1][3] += a1 * bv.w;
            }
            __syncthreads();
        }
#pragma unroll
        for (int r = 0; r < 2; ++r) {
            int gm = bm + ty * 2 + r;
            *(float4*)&B1[(size_t)gm * NHID + bn + tx * 4] =
                make_float4(acc[r][0], acc[r][1], acc[r][2], acc[r][3]);
        }
    } else if (bid < SSZ + GEMMT + 8) {
        // ---------------- u = W2 @ imp_w, 64 rows per block ------------------
        int r0 = (bid - SSZ - GEMMT) * 64;
        for (int r = r0 + w; r < r0 + 64; r += 4) {
            float p = 0.0f;
#pragma unroll
            for (int q = 0; q < 4; ++q)
                p += W2[(size_t)r * NOUT + lane + q * 64] * iw[lane + q * 64];
#pragma unroll
            for (int o = 32; o > 0; o >>= 1) p += __shfl_down(p, o, 64);
            if (lane == 0) u[r] = p;
        }
    } else {
        // ---------------- neighbor ids -> out tail; ticket reset -------------
        for (int i = t; i < NEIGH; i += 256) out[NEIGH + i] = (float)nb[i];
        if (t == 0) *ticket = 0;
    }
}

// ===== K2: fused relu-spMV (one wave per row) + last-block final ============
union SM2 {
    float su[NHID];
    struct { float sv[SSZ]; float s1[SSZ]; float s2[SSZ]; int sc[SSZ]; } fin;
};

__global__ __launch_bounds__(256) void k_back(
        const float* __restrict__ B1, const int* __restrict__ cnt,
        const unsigned short* __restrict__ cols, const float* __restrict__ u,
        const float* __restrict__ ib, float* __restrict__ v,
        int* __restrict__ ticket, float* __restrict__ out)
{
    __shared__ SM2 sm;
    __shared__ float wsum[4];
    __shared__ float sinv;
    __shared__ int lastFlag;
    const int t = threadIdx.x;
    const int w = t >> 6, lane = t & 63;
    const int bid = blockIdx.x;

    sm.su[t] = u[t];
    sm.su[t + 256] = u[t + 256];
    __syncthreads();

    // ---- spMV: v[row] = dot(relu(sum_{j in nnz(row)} B1[j,:]), u) ----------
    const int row = bid * 4 + w;                 // 528*4 == 2112 exactly
    int n = cnt[row];
    const unsigned short* cl = cols + (size_t)row * CSTR;
    float a[8] = {};
    for (int k = 0; k < n; ++k) {
        const float* br = B1 + (size_t)cl[k] * NHID;
#pragma unroll
        for (int q = 0; q < 8; ++q) a[q] += br[lane + q * 64];
    }
    float p = 0.0f;
#pragma unroll
    for (int q = 0; q < 8; ++q) p += fmaxf(a[q], 0.0f) * sm.su[lane + q * 64];
#pragma unroll
    for (int o = 32; o > 0; o >>= 1) p += __shfl_down(p, o, 64);
    if (lane == 0)
        __hip_atomic_store(&v[row], p, __ATOMIC_RELAXED, __HIP_MEMORY_SCOPE_AGENT);

    // ---- release our v writes, take a ticket; last block runs the final ----
    __threadfence();
    __syncthreads();
    if (t == 0) {
        int old = __hip_atomic_fetch_add(ticket, 1, __ATOMIC_ACQ_REL,
                                         __HIP_MEMORY_SCOPE_AGENT);
        lastFlag = (old == K2BLK - 1);
    }
    __syncthreads();
    if (!lastFlag) return;
    __threadfence();

    // ---- final: s1 = A@v, s2 = A@s1 + b, L1 normalize, emit ---------------
    for (int i = t; i < SSZ; i += 256) {
        sm.fin.sv[i] = __hip_atomic_load(&v[i], __ATOMIC_RELAXED,
                                         __HIP_MEMORY_SCOPE_AGENT);
        sm.fin.sc[i] = cnt[i];
    }
    __syncthreads();
    for (int i = t; i < SSZ; i += 256) {
        const unsigned short* cl2 = cols + (size_t)i * CSTR;
        int ni = sm.fin.sc[i];
        float s = 0.0f;
        for (int k = 0; k < ni; ++k) s += sm.fin.sv[cl2[k]];
        sm.fin.s1[i] = s;
    }
    __syncthreads();
    float bias = ib[0];
    for (int i = t; i < SSZ; i += 256) {
        const unsigned short* cl2 = cols + (size_t)i * CSTR;
        int ni = sm.fin.sc[i];
        float s = 0.0f;
        for (int k = 0; k < ni; ++k) s += sm.fin.s1[cl2[k]];
        sm.fin.s2[i] = s + bias;
    }
    __syncthreads();
    float s = 0.0f;
    for (int i = t; i < SSZ; i += 256) s += fabsf(sm.fin.s2[i]);
#pragma unroll
    for (int o = 32; o > 0; o >>= 1) s += __shfl_down(s, o, 64);
    if ((t & 63) == 0) wsum[t >> 6] = s;
    __syncthreads();
    if (t == 0) sinv = 1.0f / fmaxf(wsum[0] + wsum[1] + wsum[2] + wsum[3], 1e-12f);
    __syncthreads();
    for (int i = t; i < NEIGH; i += 256) out[i] = sm.fin.s2[NACT + i] * sinv;
}

// --------------------------------------------------------------------------
extern "C" void kernel_launch(void* const* d_in, const int* in_sizes, int n_in,
                              void* d_out, int out_size, void* d_ws, size_t ws_size,
                              hipStream_t stream) {
    const float* x   = (const float*)d_in[0];
    const float* adj = (const float*)d_in[1];
    const int*   act = (const int*)d_in[2];
    const int*   nb  = (const int*)d_in[3];
    const float* W1  = (const float*)d_in[4];
    const float* W2  = (const float*)d_in[5];
    const float* iw  = (const float*)d_in[6];
    const float* ib  = (const float*)d_in[7];
    float* out = (float*)d_out;

    // workspace layout (bytes) — total ~4.62 MB
    char* ws = (char*)d_ws;
    int*            cnt    = (int*)           (ws + 0);        // 8448 B
    unsigned short* cols   = (unsigned short*)(ws + 8704);     // 270336 B
    float*          B1     = (float*)         (ws + 279040);   // 4.33 MB
    float*          u      = (float*)         (ws + 4604416);  // 2 KB
    float*          v      = (float*)         (ws + 4606464);  // 8448 B
    int*            ticket = (int*)           (ws + 4614912);  // 4 B

    k_front<<<dim3(K1BLK), 256, 0, stream>>>(adj, act, nb, x, W1, W2, iw,
                                             cnt, cols, B1, u, out, ticket);
    k_back <<<dim3(K2BLK), 256, 0, stream>>>(B1, cnt, cols, u, ib, v,
                                             ticket, out);
}

// Round 6
// 108.240 us; speedup vs baseline: 1.6415x; 1.6415x over previous
//
#include <hip/hip_runtime.h>

#define NTOT  16384
#define NFEAT 300
#define NHID  512
#define NOUT  256
#define NACT  64
#define NEIGH 2048
#define SSZ   2112   // NACT + NEIGH
#define CSTR  64     // cols row stride
#define GEMMT 528    // 66 x 8 tiles of 32x64
#define K1BLK (SSZ + GEMMT + 8 + 1)   // 2649

union SM1 {
    struct { int scur[2304]; unsigned long long smask[9][4]; int spre[40]; } scan;
    struct { float As[16][36]; float Bs[16][64]; } gemm;
};

// ===== K1: scan (blocks <SSZ) || gemm || u=W2@iw || nb-out ==================
__global__ __launch_bounds__(256) void k_front(
        const float* __restrict__ adj, const int* __restrict__ act,
        const int* __restrict__ nb,  const float* __restrict__ x,
        const float* __restrict__ W1, const float* __restrict__ W2,
        const float* __restrict__ iw,
        int* __restrict__ cnt, unsigned short* __restrict__ cols,
        float* __restrict__ B1, float* __restrict__ u,
        float* __restrict__ out)
{
    __shared__ SM1 sm;
    const int t = threadIdx.x;
    const int w = t >> 6, lane = t & 63;
    const int bid = blockIdx.x;

    if (bid < SSZ) {
        // ---------------- ballot scan, one subgraph row per block ----------
        for (int k = t; k < 2304; k += 256)
            sm.scan.scur[k] = (k < NACT) ? act[k] : (k < SSZ ? nb[k - NACT] : 0);
        __syncthreads();
        const int row = bid;
        const float* arow = adj + (size_t)sm.scan.scur[row] * NTOT;
        float val[9];
#pragma unroll
        for (int k = 0; k < 9; ++k) val[k] = arow[sm.scan.scur[t + (k << 8)]];
        bool hit[9];
#pragma unroll
        for (int k = 0; k < 9; ++k) {
            int j = t + (k << 8);
            hit[k] = (j < SSZ) && (val[k] != 0.0f);
            unsigned long long m = __ballot(hit[k]);
            if (lane == 0) sm.scan.smask[k][w] = m;
        }
        __syncthreads();
        if (t < 64) {                            // prefix over 36 groups
            int c = (t < 36) ? __popcll(sm.scan.smask[t >> 2][t & 3]) : 0;
            int vv = c;
#pragma unroll
            for (int o = 1; o < 64; o <<= 1) {
                int xx = __shfl_up(vv, o, 64);
                if (lane >= o) vv += xx;
            }
            if (t == 0) sm.scan.spre[0] = 0;
            if (t < 36) sm.scan.spre[t + 1] = vv;
        }
        __syncthreads();
        unsigned short* dst = cols + (size_t)row * CSTR;
#pragma unroll
        for (int k = 0; k < 9; ++k) {
            if (hit[k]) {
                unsigned long long below = sm.scan.smask[k][w] & ((1ull << lane) - 1ull);
                dst[sm.scan.spre[k * 4 + w] + __popcll(below)] =
                    (unsigned short)(t + (k << 8));
            }
        }
        if (t == 0) cnt[row] = sm.scan.spre[36];
    } else if (bid < SSZ + GEMMT) {
        // ---------------- GEMM tile 32x64 of X[cur] @ W1 --------------------
        int it = bid - SSZ;
        int bm = (it % 66) * 32, bn = (it / 66) * 64;
        int tx = t & 15, ty = t >> 4;
        float acc[2][4] = {};
        for (int kt = 0; kt < NFEAT; kt += 16) {
#pragma unroll
            for (int l = 0; l < 2; ++l) {
                int idx = t + l * 256;
                int m = idx >> 4, kk = idx & 15;
                int gk = kt + kk, gm = bm + m;
                int ar = (gm < NACT) ? act[gm] : nb[gm - NACT];
                sm.gemm.As[kk][m] = (gk < NFEAT) ? x[(size_t)ar * NFEAT + gk] : 0.0f;
            }
#pragma unroll
            for (int l = 0; l < 4; ++l) {
                int idx = t + l * 256;
                int nn = idx & 63, kk = idx >> 6;
                int gk = kt + kk;
                sm.gemm.Bs[kk][nn] = (gk < NFEAT) ? W1[(size_t)gk * NHID + bn + nn] : 0.0f;
            }
            __syncthreads();
#pragma unroll
            for (int kk = 0; kk < 16; ++kk) {
                float a0 = sm.gemm.As[kk][ty * 2], a1 = sm.gemm.As[kk][ty * 2 + 1];
                float4 bv = *(const float4*)&sm.gemm.Bs[kk][tx * 4];
                acc[0][0] += a0 * bv.x; acc[0][1] += a0 * bv.y;
                acc[0][2] += a0 * bv.z; acc[0][3] += a0 * bv.w;
                acc[1][0] += a1 * bv.x; acc[1][1] += a1 * bv.y;
                acc[1][2] += a1 * bv.z; acc[1][3] += a1 * bv.w;
            }
            __syncthreads();
        }
#pragma unroll
        for (int r = 0; r < 2; ++r) {
            int gm = bm + ty * 2 + r;
            *(float4*)&B1[(size_t)gm * NHID + bn + tx * 4] =
                make_float4(acc[r][0], acc[r][1], acc[r][2], acc[r][3]);
        }
    } else if (bid < SSZ + GEMMT + 8) {
        // ---------------- u = W2 @ imp_w, 64 rows per block ------------------
        int r0 = (bid - SSZ - GEMMT) * 64;
        for (int r = r0 + w; r < r0 + 64; r += 4) {
            float p = 0.0f;
#pragma unroll
            for (int q = 0; q < 4; ++q)
                p += W2[(size_t)r * NOUT + lane + q * 64] * iw[lane + q * 64];
#pragma unroll
            for (int o = 32; o > 0; o >>= 1) p += __shfl_down(p, o, 64);
            if (lane == 0) u[r] = p;
        }
    } else {
        // ---------------- neighbor ids -> out tail ---------------------------
        for (int i = t; i < NEIGH; i += 256) out[NEIGH + i] = (float)nb[i];
    }
}

// ===== K2: fused relu-spMV, one block per row ================================
__global__ __launch_bounds__(256) void k_spmv(const float* __restrict__ B1,
                                              const int* __restrict__ cnt,
                                              const unsigned short* __restrict__ cols,
                                              const float* __restrict__ u,
                                              float* __restrict__ v) {
    __shared__ float su[NHID];
    __shared__ float wsum[4];
    int t = threadIdx.x, row = blockIdx.x;
    su[t] = u[t]; su[t + 256] = u[t + 256];

    int n = cnt[row];
    const unsigned short* cl = cols + (size_t)row * CSTR;
    float a0 = 0.0f, a1 = 0.0f;
    for (int k = 0; k < n; ++k) {
        int j = cl[k];
        a0 += B1[(size_t)j * NHID + t];
        a1 += B1[(size_t)j * NHID + t + 256];
    }
    __syncthreads();
    float p = fmaxf(a0, 0.0f) * su[t] + fmaxf(a1, 0.0f) * su[t + 256];
#pragma unroll
    for (int o = 32; o > 0; o >>= 1) p += __shfl_down(p, o, 64);
    if ((t & 63) == 0) wsum[t >> 6] = p;
    __syncthreads();
    if (t == 0) v[row] = wsum[0] + wsum[1] + wsum[2] + wsum[3];
}

// ===== K3: final, single block x 1024 =======================================
__global__ __launch_bounds__(1024) void k_final(const int* __restrict__ cnt,
                                                const unsigned short* __restrict__ cols,
                                                const float* __restrict__ v,
                                                const float* __restrict__ ib,
                                                float* __restrict__ out) {
    __shared__ float sv[SSZ];
    __shared__ float s1[SSZ];
    __shared__ float s2[SSZ];
    __shared__ int   sc[SSZ];
    __shared__ float wsum[16];
    __shared__ float inv;
    int t = threadIdx.x;
    for (int i = t; i < SSZ; i += 1024) { sv[i] = v[i]; sc[i] = cnt[i]; }
    __syncthreads();
    for (int i = t; i < SSZ; i += 1024) {
        const unsigned short* cl = cols + (size_t)i * CSTR;
        int n = sc[i];
        float s = 0.0f;
        for (int k = 0; k < n; ++k) s += sv[cl[k]];
        s1[i] = s;
    }
    __syncthreads();
    float bias = ib[0];
    for (int i = t; i < SSZ; i += 1024) {
        const unsigned short* cl = cols + (size_t)i * CSTR;
        int n = sc[i];
        float s = 0.0f;
        for (int k = 0; k < n; ++k) s += s1[cl[k]];
        s2[i] = s + bias;
    }
    __syncthreads();
    float s = 0.0f;
    for (int i = t; i < SSZ; i += 1024) s += fabsf(s2[i]);
#pragma unroll
    for (int o = 32; o > 0; o >>= 1) s += __shfl_down(s, o, 64);
    if ((t & 63) == 0) wsum[t >> 6] = s;
    __syncthreads();
    if (t == 0) {
        float tot = 0.0f;
#pragma unroll
        for (int k = 0; k < 16; ++k) tot += wsum[k];
        inv = 1.0f / fmaxf(tot, 1e-12f);
    }
    __syncthreads();
    for (int i = t; i < NEIGH; i += 1024) out[i] = s2[NACT + i] * inv;
}

// --------------------------------------------------------------------------
extern "C" void kernel_launch(void* const* d_in, const int* in_sizes, int n_in,
                              void* d_out, int out_size, void* d_ws, size_t ws_size,
                              hipStream_t stream) {
    const float* x   = (const float*)d_in[0];
    const float* adj = (const float*)d_in[1];
    const int*   act = (const int*)d_in[2];
    const int*   nb  = (const int*)d_in[3];
    const float* W1  = (const float*)d_in[4];
    const float* W2  = (const float*)d_in[5];
    const float* iw  = (const float*)d_in[6];
    const float* ib  = (const float*)d_in[7];
    float* out = (float*)d_out;

    // workspace layout (bytes) — total ~4.62 MB
    char* ws = (char*)d_ws;
    int*            cnt  = (int*)           (ws + 0);        // 8448 B
    unsigned short* cols = (unsigned short*)(ws + 8704);     // 270336 B
    float*          B1   = (float*)         (ws + 279040);   // 4.33 MB
    float*          u    = (float*)         (ws + 4604416);  // 2 KB
    float*          v    = (float*)         (ws + 4606464);  // 8448 B

    k_front<<<dim3(K1BLK), 256,  0, stream>>>(adj, act, nb, x, W1, W2, iw,
                                              cnt, cols, B1, u, out);
    k_spmv <<<dim3(SSZ),   256,  0, stream>>>(B1, cnt, cols, u, v);
    k_final<<<dim3(1),     1024, 0, stream>>>(cnt, cols, v, ib, out);
}